// Round 14
// baseline (272.031 us; speedup 1.0000x reference)
//
#include <hip/hip_runtime.h>

typedef unsigned short u16;
typedef _Float16 f16x8 __attribute__((ext_vector_type(8)));
typedef short bf16x8 __attribute__((ext_vector_type(8)));
typedef float f32x16 __attribute__((ext_vector_type(16)));
typedef unsigned int u32x4 __attribute__((ext_vector_type(4)));
typedef unsigned int u32x2 __attribute__((ext_vector_type(2)));

#define LOG2E 1.44269504088896340736f

static __device__ __forceinline__ u16 f2h(float f){
  union { _Float16 h; u16 u; } v; v.h = (_Float16)f; return v.u;
}
static __device__ __forceinline__ u16 f2bf(float f){
  union { float f; unsigned u; } v; v.f = f;
  return (u16)((v.u + 0x7fffu + ((v.u >> 16) & 1u)) >> 16);
}
static __device__ __forceinline__ unsigned pk2bf(float lo, float hi){
  unsigned r; asm("v_cvt_pk_bf16_f32 %0, %1, %2" : "=v"(r) : "v"(lo), "v"(hi)); return r;
}
static __device__ __forceinline__ float ex2(float x){
#if __has_builtin(__builtin_amdgcn_exp2f)
  return __builtin_amdgcn_exp2f(x);
#else
  return exp2f(x);
#endif
}
#define PSWAP(a, b) asm("v_permlane32_swap_b32 %0, %1" : "+v"(a), "+v"(b))

// B=8, C=512, N=4096, MID=64
// ---------------- kernel 0: x[b][c][n] f32 -> xt[b][n][c] f16 ----------------
__global__ __launch_bounds__(256) void k_tr(const float* __restrict__ x, u16* __restrict__ xt){
  int bx = blockIdx.x;
  int nb = bx & 63, cb = (bx >> 6) & 7, b = bx >> 9;
  __shared__ u16 lt[64 * 68];
  int t = threadIdx.x;
  int cl = t >> 4, n0 = (t & 15) * 4;
  const float* xp = x + ((size_t)(b * 512 + cb * 64)) * 4096 + nb * 64;
#pragma unroll
  for (int i = 0; i < 4; ++i) {
    int c = cl + i * 16;
    float4 v = *(const float4*)(xp + (size_t)c * 4096 + n0);
    u16* d = &lt[c * 68 + n0];
    d[0] = f2h(v.x); d[1] = f2h(v.y); d[2] = f2h(v.z); d[3] = f2h(v.w);
  }
  __syncthreads();
  u16* xo = xt + ((size_t)(b * 4096 + nb * 64)) * 512 + cb * 64;
#pragma unroll
  for (int i = 0; i < 2; ++i) {
    int s = t + i * 256;
    int n = s >> 3, ch = s & 7;
    u32x4 o;
#pragma unroll
    for (int j = 0; j < 4; ++j) {
      u16 a = lt[(ch * 8 + 2 * j) * 68 + n];
      u16 bb = lt[(ch * 8 + 2 * j + 1) * 68 + n];
      o[j] = (unsigned)a | ((unsigned)bb << 16);
    }
    *(u32x4*)(xo + (size_t)n * 512 + ch * 8) = o;
  }
}

// ------------- kernel 1: qk[b][n][0..64)=Q=Xt*(LOG2E*Wb)^T, [64..128)=K=Xt*Wc^T -------------
__global__ __launch_bounds__(512) void k_pqk(const u16* __restrict__ xt, const float* __restrict__ wb,
                                             const float* __restrict__ wc, u16* __restrict__ qk){
  int bx = blockIdx.x;
  int nb = bx & 31, b = bx >> 5;
  __shared__ u16 lx[128 * 64];
  __shared__ u16 lw[128 * 64];
  int t = threadIdx.x, w = t >> 6, l = t & 63, hi = l >> 5, ln = l & 31;
  int wr = w >> 1, wcol = w & 1;
  f32x16 acc[2] = {};
  for (int kt = 0; kt < 8; ++kt) {
    int c0 = kt * 64;
#pragma unroll
    for (int i = 0; i < 2; ++i) {
      int s = t + i * 512; int row = s >> 3, ch = s & 7;
      u32x4 v = *(const u32x4*)(xt + ((size_t)(b * 4096 + nb * 128 + row)) * 512 + c0 + ch * 8);
      *(u32x4*)((char*)lx + ((row * 128 + ch * 16) ^ ((row & 7) << 4))) = v;
    }
#pragma unroll
    for (int i = 0; i < 4; ++i) {
      int s = t + i * 512; int row = s >> 4, c4 = s & 15;
      const float* src = (row < 64) ? (wb + (size_t)row * 512 + c0 + c4 * 4)
                                    : (wc + (size_t)(row - 64) * 512 + c0 + c4 * 4);
      float4 v = *(const float4*)src;
      float sc = (row < 64) ? LOG2E : 1.0f;
      unsigned lo = (unsigned)f2h(v.x * sc) | ((unsigned)f2h(v.y * sc) << 16);
      unsigned h2 = (unsigned)f2h(v.z * sc) | ((unsigned)f2h(v.w * sc) << 16);
      unsigned long long qv = ((unsigned long long)h2 << 32) | lo;
      *(unsigned long long*)((char*)lw + ((row * 128 + c4 * 8) ^ ((row & 7) << 4))) = qv;
    }
    __syncthreads();
#pragma unroll
    for (int cc = 0; cc < 4; ++cc) {
      int ra = wr * 32 + ln;
      f16x8 a = *(const f16x8*)((char*)lx + ((ra * 128 + cc * 32 + hi * 16) ^ ((ra & 7) << 4)));
#pragma unroll
      for (int mt = 0; mt < 2; ++mt) {
        int rb = wcol * 64 + mt * 32 + ln;
        f16x8 bb = *(const f16x8*)((char*)lw + ((rb * 128 + cc * 32 + hi * 16) ^ ((rb & 7) << 4)));
        acc[mt] = __builtin_amdgcn_mfma_f32_32x32x16_f16(a, bb, acc[mt], 0, 0, 0);
      }
    }
    __syncthreads();
  }
#pragma unroll
  for (int mt = 0; mt < 2; ++mt)
#pragma unroll
    for (int r = 0; r < 16; ++r) {
      int n = wr * 32 + (r & 3) + 8 * (r >> 2) + 4 * hi;
      int m = wcol * 64 + mt * 32 + ln;
      qk[((size_t)(b * 4096 + nb * 128 + n)) * 128 + m] = f2h(acc[mt][r]);
    }
}

// ------------- kernel 2: vt[b][o][n] = (Wd * Xt^T), bf16 output -------------
__global__ __launch_bounds__(512) void k_pv(const u16* __restrict__ xt, const float* __restrict__ wd,
                                            u16* __restrict__ vt){
  int bx = blockIdx.x;
  int nb = bx & 31, ob = (bx >> 5) & 3, b = bx >> 7;
  __shared__ u16 lx[128 * 64];
  __shared__ u16 lw[128 * 64];
  int t = threadIdx.x, w = t >> 6, l = t & 63, hi = l >> 5, ln = l & 31;
  int wr = w >> 2, wn = w & 3;
  f32x16 acc[2] = {};
  for (int kt = 0; kt < 8; ++kt) {
    int c0 = kt * 64;
#pragma unroll
    for (int i = 0; i < 2; ++i) {
      int s = t + i * 512; int row = s >> 3, ch = s & 7;
      u32x4 v = *(const u32x4*)(xt + ((size_t)(b * 4096 + nb * 128 + row)) * 512 + c0 + ch * 8);
      *(u32x4*)((char*)lx + ((row * 128 + ch * 16) ^ ((row & 7) << 4))) = v;
    }
#pragma unroll
    for (int i = 0; i < 4; ++i) {
      int s = t + i * 512; int row = s >> 4, c4 = s & 15;
      const float* src = wd + (size_t)(ob * 128 + row) * 512 + c0 + c4 * 4;
      float4 v = *(const float4*)src;
      unsigned lo = (unsigned)f2h(v.x) | ((unsigned)f2h(v.y) << 16);
      unsigned h2 = (unsigned)f2h(v.z) | ((unsigned)f2h(v.w) << 16);
      unsigned long long qv = ((unsigned long long)h2 << 32) | lo;
      *(unsigned long long*)((char*)lw + ((row * 128 + c4 * 8) ^ ((row & 7) << 4))) = qv;
    }
    __syncthreads();
#pragma unroll
    for (int cc = 0; cc < 4; ++cc) {
      int rb = wn * 32 + ln;
      f16x8 bb = *(const f16x8*)((char*)lx + ((rb * 128 + cc * 32 + hi * 16) ^ ((rb & 7) << 4)));
#pragma unroll
      for (int ot = 0; ot < 2; ++ot) {
        int ra = wr * 64 + ot * 32 + ln;
        f16x8 a = *(const f16x8*)((char*)lw + ((ra * 128 + cc * 32 + hi * 16) ^ ((ra & 7) << 4)));
        acc[ot] = __builtin_amdgcn_mfma_f32_32x32x16_f16(a, bb, acc[ot], 0, 0, 0);
      }
    }
    __syncthreads();
  }
#pragma unroll
  for (int ot = 0; ot < 2; ++ot)
#pragma unroll
    for (int r = 0; r < 16; ++r) {
      int o = ob * 128 + wr * 64 + ot * 32 + (r & 3) + 8 * (r >> 2) + 4 * hi;
      int n = nb * 128 + wn * 32 + ln;
      vt[((size_t)(b * 512 + o)) * 4096 + n] = f2bf(acc[ot][r]);
    }
}

// ------------- kernel 3: flash attention, 4-wave blocks x 2/CU, k-tile 32, o-chunk 256 -------------
// P = exp2(S), no max/stats. grid 512 XCD-chunked (2 blocks/CU -> cross-block phase diversity).
// q-tile 128 (4 waves x 32q); 128 k-iters of 32 keys. K rows 136B stride, V rows 72B stride
// (dword strides 34,18 == 2 mod 32 -> 2-way conflicts = free). b64 reads. Double-buffered.
__global__ __launch_bounds__(256, 2) void k_attn2(const u16* __restrict__ qk, const u16* __restrict__ vt,
                                                  const float* __restrict__ x, const float* __restrict__ gamma,
                                                  float* __restrict__ out){
  __shared__ char smem[45568];   // buf[i] at i*22784: K 32x136 @+0 (4352B), V 256x72 @+4352
  int bx = blockIdx.x;
  int orig = (bx & 7) * 64 + (bx >> 3);
  int b = orig >> 6, oc2 = (orig >> 5) & 1, qt = orig & 31;
  int obase = oc2 * 256;
  int t = threadIdx.x, w = t >> 6, l = t & 63, hi = l >> 5, ln = l & 31;
  int q = qt * 128 + w * 32 + ln;
  size_t b4096 = (size_t)b * 4096;
  // Q B-fragments (log2e folded in k_pqk)
  f16x8 qf[4];
  {
    const u16* qrow = qk + (b4096 + q) * 128;
#pragma unroll
    for (int ch = 0; ch < 4; ++ch) qf[ch] = *(const f16x8*)(qrow + ch * 16 + hi * 8);
  }
  // staging roles (256 threads): K 256 slots (1/thread), V 1024 slots (4/thread)
  int rK = t >> 3, chK = t & 7;        // K row 0..31, 16B chunk 0..7
  int rV = t >> 2, ch4 = t & 3;        // V row base 0..63, 16B chunk 0..3
  unsigned kW = (unsigned)(rK * 136 + chK * 16);
  unsigned vW = (unsigned)(4352 + rV * 72 + ch4 * 16);
  // fragment read offsets
  unsigned rbK[4];                      // QK: K[ln][cc*32 + hi*16]
#pragma unroll
  for (int cc = 0; cc < 4; ++cc) rbK[cc] = (unsigned)(ln * 136 + cc * 32 + hi * 16);
  unsigned rbV[2];                      // PV: V[ot*32+ln][kc*32 + hi*16], ot adds 32*72
#pragma unroll
  for (int kc = 0; kc < 2; ++kc) rbV[kc] = (unsigned)(4352 + ln * 72 + kc * 32 + hi * 16);
  // global staging pointers
  const u16* gK = qk + (b4096 + rK) * 128 + 64 + chK * 8;
  const u16* gV0 = vt + ((size_t)(b * 512 + obase + rV)) * 4096 + ch4 * 8;
  const u16* gV1 = gV0 + (size_t)64 * 4096;
  const u16* gV2 = gV0 + (size_t)128 * 4096;
  const u16* gV3 = gV0 + (size_t)192 * 4096;
  u32x4 kreg = *(const u32x4*)gK;
  u32x4 vr0 = *(const u32x4*)gV0, vr1 = *(const u32x4*)gV1;
  u32x4 vr2 = *(const u32x4*)gV2, vr3 = *(const u32x4*)gV3;
  // prologue: write tile 0 into buf0 (b64-split stores, 8B-aligned)
  {
    char* bp = smem;
    *(u32x2*)(bp + kW)              = u32x2{kreg[0], kreg[1]};
    *(u32x2*)(bp + kW + 8)          = u32x2{kreg[2], kreg[3]};
    *(u32x2*)(bp + vW)              = u32x2{vr0[0], vr0[1]};
    *(u32x2*)(bp + vW + 8)          = u32x2{vr0[2], vr0[3]};
    *(u32x2*)(bp + vW + 4608)       = u32x2{vr1[0], vr1[1]};   // +64 rows = 64*72
    *(u32x2*)(bp + vW + 4616)       = u32x2{vr1[2], vr1[3]};
    *(u32x2*)(bp + vW + 9216)       = u32x2{vr2[0], vr2[1]};
    *(u32x2*)(bp + vW + 9224)       = u32x2{vr2[2], vr2[3]};
    *(u32x2*)(bp + vW + 13824)      = u32x2{vr3[0], vr3[1]};
    *(u32x2*)(bp + vW + 13832)      = u32x2{vr3[2], vr3[3]};
  }
  gK += 4096; gV0 += 32; gV1 += 32; gV2 += 32; gV3 += 32;
  f32x16 acc[8] = {};
  float lacc = 0.0f;
  for (int kt = 0; kt < 128; ++kt) {
    __syncthreads();   // buf[kt&1] writes visible; prior reads of buf[(kt+1)&1] complete
    char* bufp = smem + (kt & 1) * 22784;
    char* bufn = smem + ((kt + 1) & 1) * 22784;
    if (kt < 127) {    // issue next-tile loads; latency hides under compute
      kreg = *(const u32x4*)gK;
      vr0 = *(const u32x4*)gV0; vr1 = *(const u32x4*)gV1;
      vr2 = *(const u32x4*)gV2; vr3 = *(const u32x4*)gV3;
      gK += 4096; gV0 += 32; gV1 += 32; gV2 += 32; gV3 += 32;
    }
    // S^T = K * Q^T : 4 MFMAs; lane holds 16 scores (keys) for q=ln
    f32x16 s0 = {};
    __builtin_amdgcn_s_setprio(1);
#pragma unroll
    for (int cc = 0; cc < 4; ++cc) {
      union { u32x2 d[2]; f16x8 v; } k0;
      const char* p0 = bufp + rbK[cc];
      k0.d[0] = *(const u32x2*)p0;  k0.d[1] = *(const u32x2*)(p0 + 8);
      s0 = __builtin_amdgcn_mfma_f32_32x32x16_f16(k0.v, qf[cc], s0, 0, 0, 0);
    }
    __builtin_amdgcn_s_setprio(0);
    // 2 interleaved blocks: {exp2 x8, sum, pack pa (k=16), 8 PV MFMA}
    float psum = 0.0f;
#pragma unroll
    for (int blk = 0; blk < 2; ++blk) {
      const int base = blk * 8;
      float e[8];
#pragma unroll
      for (int j = 0; j < 8; ++j) e[j] = ex2(s0[base + j]);
      psum += ((e[0] + e[1]) + (e[2] + e[3])) + ((e[4] + e[5]) + (e[6] + e[7]));
      unsigned c[4];
      c[0] = pk2bf(e[0], e[1]); c[1] = pk2bf(e[2], e[3]);
      c[2] = pk2bf(e[4], e[5]); c[3] = pk2bf(e[6], e[7]);
      PSWAP(c[0], c[2]); PSWAP(c[1], c[3]);
      union U8 { unsigned u[4]; bf16x8 v; } pa;
      pa.u[0] = c[0]; pa.u[1] = c[1]; pa.u[2] = c[2]; pa.u[3] = c[3];
      const char* pv = bufp + rbV[blk];
      __builtin_amdgcn_s_setprio(1);
#pragma unroll
      for (int ot = 0; ot < 8; ++ot) {
        union { u32x2 d[2]; bf16x8 v; } vb;
        const char* p = pv + ot * 2304;   // 32 rows * 72 B
        vb.d[0] = *(const u32x2*)p;  vb.d[1] = *(const u32x2*)(p + 8);
        acc[ot] = __builtin_amdgcn_mfma_f32_32x32x16_bf16(pa.v, vb.v, acc[ot], 0, 0, 0);
      }
      __builtin_amdgcn_s_setprio(0);
    }
    lacc += psum;
    // tail: write next tile into the other buffer
    if (kt < 127) {
      *(u32x2*)(bufn + kW)              = u32x2{kreg[0], kreg[1]};
      *(u32x2*)(bufn + kW + 8)          = u32x2{kreg[2], kreg[3]};
      *(u32x2*)(bufn + vW)              = u32x2{vr0[0], vr0[1]};
      *(u32x2*)(bufn + vW + 8)          = u32x2{vr0[2], vr0[3]};
      *(u32x2*)(bufn + vW + 4608)       = u32x2{vr1[0], vr1[1]};
      *(u32x2*)(bufn + vW + 4616)       = u32x2{vr1[2], vr1[3]};
      *(u32x2*)(bufn + vW + 9216)       = u32x2{vr2[0], vr2[1]};
      *(u32x2*)(bufn + vW + 9224)       = u32x2{vr2[2], vr2[3]};
      *(u32x2*)(bufn + vW + 13824)      = u32x2{vr3[0], vr3[1]};
      *(u32x2*)(bufn + vW + 13832)      = u32x2{vr3[2], vr3[3]};
    }
  }
  // epilogue: l per q-row, scale = gamma/l; transpose 32x32 tiles via per-wave LDS; coalesced store
  float l_tot = lacc + __shfl_xor(lacc, 32);
  float sinv = gamma[0] / l_tot;
  __syncthreads();
  float* tb = (float*)smem + w * 1056;  // per-wave 32x33 f32
#pragma unroll
  for (int ot = 0; ot < 8; ++ot) {
#pragma unroll
    for (int r = 0; r < 16; ++r) {
      int qr = (r & 3) + 8 * (r >> 2) + 4 * hi;
      tb[ln * 33 + qr] = acc[ot][r];
    }
#pragma unroll
    for (int it = 0; it < 16; ++it) {
      int orow = it * 2 + hi;
      float v = tb[orow * 33 + ln];
      size_t gi = (((size_t)(b * 512 + obase + ot * 32 + orow)) << 12) + (size_t)(qt * 128 + w * 32 + ln);
      out[gi] = sinv * v + x[gi];
    }
    __syncthreads();
  }
}

extern "C" void kernel_launch(void* const* d_in, const int* in_sizes, int n_in,
                              void* d_out, int out_size, void* d_ws, size_t ws_size,
                              hipStream_t stream) {
  (void)in_sizes; (void)n_in; (void)out_size; (void)ws_size;
  const float* x     = (const float*)d_in[0];
  const float* wb    = (const float*)d_in[1];
  const float* wc    = (const float*)d_in[2];
  const float* wd    = (const float*)d_in[3];
  const float* gamma = (const float*)d_in[4];
  float* out = (float*)d_out;
  char* ws = (char*)d_ws;
  u16* xt  = (u16*)ws;                    // 32 MB: Xt f16 [B][N][C]
  u16* qkb = (u16*)(ws + 33554432);       //  8 MB: [B][N][Q(64)|K(64)] f16
  u16* vtb = (u16*)(ws + 41943040);       // 32 MB: V^T bf16 [B][C][N]
  k_tr   <<<dim3(4096), dim3(256), 0, stream>>>(x, xt);
  k_pqk  <<<dim3(256),  dim3(512), 0, stream>>>(xt, wb, wc, qkb);
  k_pv   <<<dim3(1024), dim3(512), 0, stream>>>(xt, wd, vtb);
  k_attn2<<<dim3(512),  dim3(256), 0, stream>>>(qkb, vtb, x, gamma, out);
}

// Round 15
// 237.076 us; speedup vs baseline: 1.1474x; 1.1474x over previous
//
#include <hip/hip_runtime.h>

typedef unsigned short u16;
typedef _Float16 f16x8 __attribute__((ext_vector_type(8)));
typedef short bf16x8 __attribute__((ext_vector_type(8)));
typedef float f32x16 __attribute__((ext_vector_type(16)));
typedef unsigned int u32x4 __attribute__((ext_vector_type(4)));
typedef unsigned int u32x2 __attribute__((ext_vector_type(2)));

#define LOG2E 1.44269504088896340736f

static __device__ __forceinline__ u16 f2h(float f){
  union { _Float16 h; u16 u; } v; v.h = (_Float16)f; return v.u;
}
static __device__ __forceinline__ u16 f2bf(float f){
  union { float f; unsigned u; } v; v.f = f;
  return (u16)((v.u + 0x7fffu + ((v.u >> 16) & 1u)) >> 16);
}
static __device__ __forceinline__ unsigned pk2bf(float lo, float hi){
  unsigned r; asm("v_cvt_pk_bf16_f32 %0, %1, %2" : "=v"(r) : "v"(lo), "v"(hi)); return r;
}
static __device__ __forceinline__ float ex2(float x){
#if __has_builtin(__builtin_amdgcn_exp2f)
  return __builtin_amdgcn_exp2f(x);
#else
  return exp2f(x);
#endif
}
#define PSWAP(a, b) asm("v_permlane32_swap_b32 %0, %1" : "+v"(a), "+v"(b))

// B=8, C=512, N=4096, MID=64
// ---- kernel 0: w16[640][512] f16 = [Wd(512) ; LOG2E*Wb(64) ; Wc(64)] ----
__global__ __launch_bounds__(256) void k_wcvt(const float* __restrict__ wb, const float* __restrict__ wc,
                                              const float* __restrict__ wd, u16* __restrict__ w16){
  int row = blockIdx.x, t = threadIdx.x;
  const float* src; float sc;
  if (row < 512)      { src = wd + (size_t)row * 512;        sc = 1.0f;  }
  else if (row < 576) { src = wb + (size_t)(row - 512) * 512; sc = LOG2E; }
  else                { src = wc + (size_t)(row - 576) * 512; sc = 1.0f;  }
  float2 v = *(const float2*)(src + t * 2);
  unsigned pk = (unsigned)f2h(v.x * sc) | ((unsigned)f2h(v.y * sc) << 16);
  *(unsigned*)(w16 + (size_t)row * 512 + t * 2) = pk;
}

// ---- kernel 1: fused projections. Reads x directly; writes qkb[b][n][128] f16 and
//      vtb[b][o][n] bf16. Per block (b, nb of 128 n): out rows 640 = w16 rows x Xt^T.
//      8 waves = (i = n-half of 64) x (j = row-quarter of 160). acc[5][2] tiles 32x32.
__global__ __launch_bounds__(512, 1) void k_fused(const float* __restrict__ x, const u16* __restrict__ w16,
                                                  u16* __restrict__ qkb, u16* __restrict__ vtb){
  __shared__ u16 ltmp[64 * 140];   // [c][n] f16, stride 140 u16 (280 B)
  __shared__ u16 lx[128 * 68];     // [n][c] f16, stride 68 u16 (136 B)
  __shared__ u16 lw[640 * 68];     // [row][c] f16, stride 68 u16 (136 B); reused as qkl in epilogue
  int bx = blockIdx.x;
  int b = bx >> 5, nb = bx & 31;
  int t = threadIdx.x, w = t >> 6, l = t & 63, hi = l >> 5, ln = l & 31;
  int i = w & 1, j = w >> 1;
  size_t b4096 = (size_t)b * 4096;
  f32x16 acc[5][2] = {};
  // per-thread staging roles
  int cS = t >> 3, ncS = t & 7;          // ltmp stage: c row, 16-n group
  int nT = t & 127, q4 = t >> 7;         // transpose: n, 16-c group
  for (int kt = 0; kt < 8; ++kt) {
    int c0 = kt * 64;
    // stage x -> ltmp[c][n] (f32->f16)
    {
      const float* xp = x + ((size_t)(b * 512 + c0 + cS)) * 4096 + nb * 128 + ncS * 16;
      u16* d = &ltmp[cS * 140 + ncS * 16];
#pragma unroll
      for (int g = 0; g < 4; ++g) {
        float4 v = *(const float4*)(xp + g * 4);
        unsigned lo = (unsigned)f2h(v.x) | ((unsigned)f2h(v.y) << 16);
        unsigned h2 = (unsigned)f2h(v.z) | ((unsigned)f2h(v.w) << 16);
        *(u32x2*)(d + g * 4) = u32x2{lo, h2};
      }
    }
    // stage weights (f16 pre-converted) -> lw
#pragma unroll
    for (int k10 = 0; k10 < 10; ++k10) {
      int slot = t + 512 * k10;
      int row = slot >> 3, ch8 = slot & 7;
      u32x4 wv = *(const u32x4*)(w16 + (size_t)row * 512 + c0 + ch8 * 8);
      u16* d = &lw[row * 68 + ch8 * 8];
      *(u32x2*)d       = u32x2{wv[0], wv[1]};
      *(u32x2*)(d + 4) = u32x2{wv[2], wv[3]};
    }
    __syncthreads();
    // transpose ltmp -> lx[n][c]
    {
      u16 tmp[16];
#pragma unroll
      for (int k = 0; k < 16; ++k) tmp[k] = ltmp[(q4 * 16 + k) * 140 + nT];
      u16* d = &lx[nT * 68 + q4 * 16];
#pragma unroll
      for (int g = 0; g < 4; ++g) {
        unsigned lo = (unsigned)tmp[g * 4]     | ((unsigned)tmp[g * 4 + 1] << 16);
        unsigned h2 = (unsigned)tmp[g * 4 + 2] | ((unsigned)tmp[g * 4 + 3] << 16);
        *(u32x2*)(d + g * 4) = u32x2{lo, h2};
      }
    }
    __syncthreads();
    // compute: D[row][n] += W[row][c] * Xt[n][c]
#pragma unroll
    for (int cc = 0; cc < 4; ++cc) {
      union { u32x2 d[2]; f16x8 v; } bf[2];
#pragma unroll
      for (int u = 0; u < 2; ++u) {
        const u16* p = &lx[(i * 64 + u * 32 + ln) * 68 + cc * 16 + hi * 8];
        bf[u].d[0] = *(const u32x2*)p; bf[u].d[1] = *(const u32x2*)(p + 4);
      }
#pragma unroll
      for (int s = 0; s < 5; ++s) {
        union { u32x2 d[2]; f16x8 v; } af;
        const u16* p = &lw[(j * 160 + s * 32 + ln) * 68 + cc * 16 + hi * 8];
        af.d[0] = *(const u32x2*)p; af.d[1] = *(const u32x2*)(p + 4);
#pragma unroll
        for (int u = 0; u < 2; ++u)
          acc[s][u] = __builtin_amdgcn_mfma_f32_32x32x16_f16(af.v, bf[u].v, acc[s][u], 0, 0, 0);
      }
    }
    __syncthreads();
  }
  // epilogue 1: V rows (rt < 512) -> vtb[b][o][n] bf16 (scalar stores, k_pv-proven pattern)
#pragma unroll
  for (int s = 0; s < 5; ++s) {
    int rt = j * 160 + s * 32;
    if (rt < 512) {
#pragma unroll
      for (int u = 0; u < 2; ++u) {
        int n = nb * 128 + i * 64 + u * 32 + ln;
#pragma unroll
        for (int r = 0; r < 16; ++r) {
          int o = rt + (r & 3) + 8 * (r >> 2) + 4 * hi;
          vtb[((size_t)(b * 512 + o)) * 4096 + n] = f2bf(acc[s][u][r]);
        }
      }
    }
  }
  // epilogue 2: QK rows (rt >= 512) -> qkl[n][m] f16 in LDS (over lw), then coalesced write
  u16* qkl = lw;   // 128 x 132 u16 = 33792 B <= lw region; safe: all lw reads done (barrier above)
  if (j == 3) {
#pragma unroll
    for (int s = 1; s < 5; ++s) {
      int mbase = (s - 1) * 32;
#pragma unroll
      for (int u = 0; u < 2; ++u) {
        int nl = i * 64 + u * 32 + ln;
#pragma unroll
        for (int r = 0; r < 16; ++r) {
          int m = mbase + (r & 3) + 8 * (r >> 2) + 4 * hi;
          qkl[nl * 132 + m] = f2h(acc[s][u][r]);
        }
      }
    }
  }
  __syncthreads();
  {
    int n2 = t >> 2, ch = t & 3;
    u16* dst = qkb + (b4096 + nb * 128 + n2) * 128 + ch * 32;
#pragma unroll
    for (int g = 0; g < 4; ++g) {
      u32x2 d0 = *(const u32x2*)(&qkl[n2 * 132 + ch * 32 + g * 8]);
      u32x2 d1 = *(const u32x2*)(&qkl[n2 * 132 + ch * 32 + g * 8 + 4]);
      *(u32x4*)(dst + g * 8) = u32x4{d0[0], d0[1], d1[0], d1[1]};
    }
  }
}

// ------------- kernel 2: flash attention, o-chunk 256, 136B-stride LDS (R12, 190.6 us) -------------
// P = exp2(S) directly, no max/stats. grid 256 XCD-chunked. 8 waves x 32 q; KV tile 64.
// LDS rows strided 136 B (dword-stride 34 = 2 mod 32): 8B-split reads give 2-way max (free).
// Double buffer (2 x 42.5 KB), one barrier per iter. All LDS offsets in 8B units.
__global__ __launch_bounds__(512, 1) void k_attn2(const u16* __restrict__ qk, const u16* __restrict__ vt,
                                                  const float* __restrict__ x, const float* __restrict__ gamma,
                                                  float* __restrict__ out){
  __shared__ char smem[87040];   // buf[i] at i*43520: K 64x136 @+0 (8704B), V 256x136 @+8704
  int bx = blockIdx.x;
  int orig = (bx & 7) * 32 + (bx >> 3);
  int combo = orig >> 4, qt = orig & 15;
  int b = combo >> 1, oc2 = combo & 1;
  int obase = oc2 * 256;
  int t = threadIdx.x, w = t >> 6, l = t & 63, hi = l >> 5, ln = l & 31;
  int q = qt * 256 + w * 32 + ln;
  size_t b4096 = (size_t)b * 4096;
  f16x8 qf[4];
  {
    const u16* qrow = qk + (b4096 + q) * 128;
#pragma unroll
    for (int ch = 0; ch < 4; ++ch) qf[ch] = *(const f16x8*)(qrow + ch * 16 + hi * 8);
  }
  int rowS = t >> 3, chS = t & 7;
  unsigned w8 = (unsigned)(rowS * 17 + chS * 2);
  unsigned rb8[4];
#pragma unroll
  for (int cc = 0; cc < 4; ++cc)
    rb8[cc] = (unsigned)(ln * 17 + cc * 4 + hi * 2);
  const u16* gK = qk + (b4096 + rowS) * 128 + 64 + chS * 8;
  const u16* gV0 = vt + ((size_t)(b * 512 + obase + rowS)) * 4096 + chS * 8;
  const u16* gV1 = gV0 + (size_t)64 * 4096;
  const u16* gV2 = gV0 + (size_t)128 * 4096;
  const u16* gV3 = gV0 + (size_t)192 * 4096;
  u32x4 kreg = *(const u32x4*)gK;
  u32x4 vr0 = *(const u32x4*)gV0, vr1 = *(const u32x4*)gV1;
  u32x4 vr2 = *(const u32x4*)gV2, vr3 = *(const u32x4*)gV3;
  {
    char* bp = smem;
    *(u32x2*)(bp + w8 * 8)              = u32x2{kreg[0], kreg[1]};
    *(u32x2*)(bp + w8 * 8 + 8)          = u32x2{kreg[2], kreg[3]};
    *(u32x2*)(bp + 8704  + w8 * 8)      = u32x2{vr0[0], vr0[1]};
    *(u32x2*)(bp + 8704  + w8 * 8 + 8)  = u32x2{vr0[2], vr0[3]};
    *(u32x2*)(bp + 17408 + w8 * 8)      = u32x2{vr1[0], vr1[1]};
    *(u32x2*)(bp + 17408 + w8 * 8 + 8)  = u32x2{vr1[2], vr1[3]};
    *(u32x2*)(bp + 26112 + w8 * 8)      = u32x2{vr2[0], vr2[1]};
    *(u32x2*)(bp + 26112 + w8 * 8 + 8)  = u32x2{vr2[2], vr2[3]};
    *(u32x2*)(bp + 34816 + w8 * 8)      = u32x2{vr3[0], vr3[1]};
    *(u32x2*)(bp + 34816 + w8 * 8 + 8)  = u32x2{vr3[2], vr3[3]};
  }
  gK += 8192; gV0 += 64; gV1 += 64; gV2 += 64; gV3 += 64;
  f32x16 acc[8] = {};
  float lacc = 0.0f;
  for (int kt = 0; kt < 64; ++kt) {
    __syncthreads();
    char* bufp = smem + (kt & 1) * 43520;
    char* bufn = smem + ((kt + 1) & 1) * 43520;
    if (kt < 63) {
      kreg = *(const u32x4*)gK;
      vr0 = *(const u32x4*)gV0; vr1 = *(const u32x4*)gV1;
      vr2 = *(const u32x4*)gV2; vr3 = *(const u32x4*)gV3;
      gK += 8192; gV0 += 64; gV1 += 64; gV2 += 64; gV3 += 64;
    }
    f32x16 s0 = {}, s1 = {};
    __builtin_amdgcn_s_setprio(1);
#pragma unroll
    for (int cc = 0; cc < 4; ++cc) {
      union { u32x2 d[2]; f16x8 v; } k0, k1;
      const char* p0 = bufp + rb8[cc] * 8;
      const char* p1 = p0 + 4352;
      k0.d[0] = *(const u32x2*)p0;  k0.d[1] = *(const u32x2*)(p0 + 8);
      k1.d[0] = *(const u32x2*)p1;  k1.d[1] = *(const u32x2*)(p1 + 8);
      s0 = __builtin_amdgcn_mfma_f32_32x32x16_f16(k0.v, qf[cc], s0, 0, 0, 0);
      s1 = __builtin_amdgcn_mfma_f32_32x32x16_f16(k1.v, qf[cc], s1, 0, 0, 0);
    }
    __builtin_amdgcn_s_setprio(0);
#pragma unroll
    for (int r = 0; r < 16; ++r) s0[r] = ex2(s0[r]);
#pragma unroll
    for (int r = 0; r < 16; ++r) s1[r] = ex2(s1[r]);
    {
      float p[16];
#pragma unroll
      for (int r = 0; r < 16; ++r) p[r] = s0[r] + s1[r];
#pragma unroll
      for (int d = 8; d >= 1; d >>= 1)
#pragma unroll
        for (int r = 0; r < d; ++r) p[r] += p[r + d];
      lacc += p[0];
    }
    unsigned c0[8], c1[8];
#pragma unroll
    for (int ii = 0; ii < 8; ++ii) c0[ii] = pk2bf(s0[2 * ii], s0[2 * ii + 1]);
#pragma unroll
    for (int ii = 0; ii < 8; ++ii) c1[ii] = pk2bf(s1[2 * ii], s1[2 * ii + 1]);
    PSWAP(c0[0], c0[2]); PSWAP(c0[1], c0[3]); PSWAP(c0[4], c0[6]); PSWAP(c0[5], c0[7]);
    PSWAP(c1[0], c1[2]); PSWAP(c1[1], c1[3]); PSWAP(c1[4], c1[6]); PSWAP(c1[5], c1[7]);
    union U8 { unsigned u[4]; bf16x8 v; } pa[4];
#pragma unroll
    for (int jj = 0; jj < 4; ++jj) { pa[0].u[jj] = c0[jj]; pa[1].u[jj] = c0[4 + jj]; pa[2].u[jj] = c1[jj]; pa[3].u[jj] = c1[4 + jj]; }
    __builtin_amdgcn_s_setprio(1);
#pragma unroll
    for (int kc = 0; kc < 4; ++kc) {
      const char* pv = bufp + 8704 + rb8[kc] * 8;
#pragma unroll
      for (int ot = 0; ot < 8; ++ot) {
        union { u32x2 d[2]; bf16x8 v; } vb;
        const char* p = pv + ot * 4352;
        vb.d[0] = *(const u32x2*)p;  vb.d[1] = *(const u32x2*)(p + 8);
        acc[ot] = __builtin_amdgcn_mfma_f32_32x32x16_bf16(pa[kc].v, vb.v, acc[ot], 0, 0, 0);
      }
    }
    __builtin_amdgcn_s_setprio(0);
    if (kt < 63) {
      *(u32x2*)(bufn + w8 * 8)              = u32x2{kreg[0], kreg[1]};
      *(u32x2*)(bufn + w8 * 8 + 8)          = u32x2{kreg[2], kreg[3]};
      *(u32x2*)(bufn + 8704  + w8 * 8)      = u32x2{vr0[0], vr0[1]};
      *(u32x2*)(bufn + 8704  + w8 * 8 + 8)  = u32x2{vr0[2], vr0[3]};
      *(u32x2*)(bufn + 17408 + w8 * 8)      = u32x2{vr1[0], vr1[1]};
      *(u32x2*)(bufn + 17408 + w8 * 8 + 8)  = u32x2{vr1[2], vr1[3]};
      *(u32x2*)(bufn + 26112 + w8 * 8)      = u32x2{vr2[0], vr2[1]};
      *(u32x2*)(bufn + 26112 + w8 * 8 + 8)  = u32x2{vr2[2], vr2[3]};
      *(u32x2*)(bufn + 34816 + w8 * 8)      = u32x2{vr3[0], vr3[1]};
      *(u32x2*)(bufn + 34816 + w8 * 8 + 8)  = u32x2{vr3[2], vr3[3]};
    }
  }
  float l_tot = lacc + __shfl_xor(lacc, 32);
  float sinv = gamma[0] / l_tot;
  __syncthreads();
  float* tb = (float*)smem + w * 1056;
#pragma unroll
  for (int ot = 0; ot < 8; ++ot) {
#pragma unroll
    for (int r = 0; r < 16; ++r) {
      int qr = (r & 3) + 8 * (r >> 2) + 4 * hi;
      tb[ln * 33 + qr] = acc[ot][r];
    }
#pragma unroll
    for (int it = 0; it < 16; ++it) {
      int orow = it * 2 + hi;
      float v = tb[orow * 33 + ln];
      size_t gi = (((size_t)(b * 512 + obase + ot * 32 + orow)) << 12) + (size_t)(qt * 256 + w * 32 + ln);
      out[gi] = sinv * v + x[gi];
    }
    __syncthreads();
  }
}

extern "C" void kernel_launch(void* const* d_in, const int* in_sizes, int n_in,
                              void* d_out, int out_size, void* d_ws, size_t ws_size,
                              hipStream_t stream) {
  (void)in_sizes; (void)n_in; (void)out_size; (void)ws_size;
  const float* x     = (const float*)d_in[0];
  const float* wb    = (const float*)d_in[1];
  const float* wc    = (const float*)d_in[2];
  const float* wd    = (const float*)d_in[3];
  const float* gamma = (const float*)d_in[4];
  float* out = (float*)d_out;
  char* ws = (char*)d_ws;
  u16* w16 = (u16*)ws;                    // 640 KB: fused weights f16 [640][512]
  u16* qkb = (u16*)(ws + 1048576);        //   8 MB: [B][N][Q(64)|K(64)] f16
  u16* vtb = (u16*)(ws + 9437184);        //  32 MB: V^T bf16 [B][C][N]
  k_wcvt <<<dim3(640), dim3(256), 0, stream>>>(wb, wc, wd, w16);
  k_fused<<<dim3(256), dim3(512), 0, stream>>>(x, w16, qkb, vtb);
  k_attn2<<<dim3(256), dim3(512), 0, stream>>>(qkb, vtb, x, gamma, out);
}

// Round 16
// 223.622 us; speedup vs baseline: 1.2165x; 1.0602x over previous
//
#include <hip/hip_runtime.h>

typedef unsigned short u16;
typedef _Float16 f16x8 __attribute__((ext_vector_type(8)));
typedef short bf16x8 __attribute__((ext_vector_type(8)));
typedef float f32x16 __attribute__((ext_vector_type(16)));
typedef unsigned int u32x4 __attribute__((ext_vector_type(4)));
typedef unsigned int u32x2 __attribute__((ext_vector_type(2)));

#define LOG2E 1.44269504088896340736f

static __device__ __forceinline__ u16 f2h(float f){
  union { _Float16 h; u16 u; } v; v.h = (_Float16)f; return v.u;
}
static __device__ __forceinline__ u16 f2bf(float f){
  union { float f; unsigned u; } v; v.f = f;
  return (u16)((v.u + 0x7fffu + ((v.u >> 16) & 1u)) >> 16);
}
static __device__ __forceinline__ unsigned pk2bf(float lo, float hi){
  unsigned r; asm("v_cvt_pk_bf16_f32 %0, %1, %2" : "=v"(r) : "v"(lo), "v"(hi)); return r;
}
static __device__ __forceinline__ float ex2(float x){
#if __has_builtin(__builtin_amdgcn_exp2f)
  return __builtin_amdgcn_exp2f(x);
#else
  return exp2f(x);
#endif
}
#define PSWAP(a, b) asm("v_permlane32_swap_b32 %0, %1" : "+v"(a), "+v"(b))

// B=8, C=512, N=4096, MID=64
// ---- kernel 0: w16[640][512] f16 = [Wd(512) ; LOG2E*Wb(64) ; Wc(64)] ----
__global__ __launch_bounds__(256) void k_wcvt(const float* __restrict__ wb, const float* __restrict__ wc,
                                              const float* __restrict__ wd, u16* __restrict__ w16){
  int row = blockIdx.x, t = threadIdx.x;
  const float* src; float sc;
  if (row < 512)      { src = wd + (size_t)row * 512;        sc = 1.0f;  }
  else if (row < 576) { src = wb + (size_t)(row - 512) * 512; sc = LOG2E; }
  else                { src = wc + (size_t)(row - 576) * 512; sc = 1.0f;  }
  float2 v = *(const float2*)(src + t * 2);
  unsigned pk = (unsigned)f2h(v.x * sc) | ((unsigned)f2h(v.y * sc) << 16);
  *(unsigned*)(w16 + (size_t)row * 512 + t * 2) = pk;
}

// ---- kernel 1: fused projections (x-stage double-buffered through registers). Reads x
//      directly; writes qkb[b][n][128] f16 and vtb[b][o][n] bf16. Per block (b, nb of 128 n):
//      out rows 640 = w16 rows x Xt^T. 8 waves = (i = n-half) x (j = row-quarter of 160).
__global__ __launch_bounds__(512, 1) void k_fused(const float* __restrict__ x, const u16* __restrict__ w16,
                                                  u16* __restrict__ qkb, u16* __restrict__ vtb){
  __shared__ u16 ltmp[64 * 140];   // [c][n] f16, stride 140 u16 (280 B)
  __shared__ u16 lx[128 * 68];     // [n][c] f16, stride 68 u16 (136 B)
  __shared__ u16 lw[640 * 68];     // [row][c] f16, stride 68 u16; reused as qkl in epilogue
  int bx = blockIdx.x;
  int b = bx >> 5, nb = bx & 31;
  int t = threadIdx.x, w = t >> 6, l = t & 63, hi = l >> 5, ln = l & 31;
  int i = w & 1, j = w >> 1;
  size_t b4096 = (size_t)b * 4096;
  f32x16 acc[5][2] = {};
  // per-thread staging roles
  int cS = t >> 3, ncS = t & 7;          // ltmp stage: c row, 16-n group
  int nT = t & 127, q4 = t >> 7;         // transpose: n, 16-c group
  const float* xbase = x + ((size_t)(b * 512 + cS)) * 4096 + nb * 128 + ncS * 16;
  float4 xpre[4];
#pragma unroll
  for (int g = 0; g < 4; ++g) xpre[g] = *(const float4*)(xbase + g * 4);   // prefetch kt=0
  for (int kt = 0; kt < 8; ++kt) {
    int c0 = kt * 64;
    // write prefetched x regs -> ltmp[c][n] (f32->f16)
    {
      u16* d = &ltmp[cS * 140 + ncS * 16];
#pragma unroll
      for (int g = 0; g < 4; ++g) {
        float4 v = xpre[g];
        unsigned lo = (unsigned)f2h(v.x) | ((unsigned)f2h(v.y) << 16);
        unsigned h2 = (unsigned)f2h(v.z) | ((unsigned)f2h(v.w) << 16);
        *(u32x2*)(d + g * 4) = u32x2{lo, h2};
      }
    }
    // stage weights (f16 pre-converted, L2-resident) -> lw
#pragma unroll
    for (int k10 = 0; k10 < 10; ++k10) {
      int slot = t + 512 * k10;
      int row = slot >> 3, ch8 = slot & 7;
      u32x4 wv = *(const u32x4*)(w16 + (size_t)row * 512 + c0 + ch8 * 8);
      u16* d = &lw[row * 68 + ch8 * 8];
      *(u32x2*)d       = u32x2{wv[0], wv[1]};
      *(u32x2*)(d + 4) = u32x2{wv[2], wv[3]};
    }
    __syncthreads();
    // issue next-tile x loads now; they fly under transpose + MFMA
    if (kt < 7) {
      const float* xp = xbase + (size_t)(kt + 1) * 64 * 4096;
#pragma unroll
      for (int g = 0; g < 4; ++g) xpre[g] = *(const float4*)(xp + g * 4);
    }
    // transpose ltmp -> lx[n][c]
    {
      u16 tmp[16];
#pragma unroll
      for (int k = 0; k < 16; ++k) tmp[k] = ltmp[(q4 * 16 + k) * 140 + nT];
      u16* d = &lx[nT * 68 + q4 * 16];
#pragma unroll
      for (int g = 0; g < 4; ++g) {
        unsigned lo = (unsigned)tmp[g * 4]     | ((unsigned)tmp[g * 4 + 1] << 16);
        unsigned h2 = (unsigned)tmp[g * 4 + 2] | ((unsigned)tmp[g * 4 + 3] << 16);
        *(u32x2*)(d + g * 4) = u32x2{lo, h2};
      }
    }
    __syncthreads();
    // compute: D[row][n] += W[row][c] * Xt[n][c]
#pragma unroll
    for (int cc = 0; cc < 4; ++cc) {
      union { u32x2 d[2]; f16x8 v; } bf[2];
#pragma unroll
      for (int u = 0; u < 2; ++u) {
        const u16* p = &lx[(i * 64 + u * 32 + ln) * 68 + cc * 16 + hi * 8];
        bf[u].d[0] = *(const u32x2*)p; bf[u].d[1] = *(const u32x2*)(p + 4);
      }
#pragma unroll
      for (int s = 0; s < 5; ++s) {
        union { u32x2 d[2]; f16x8 v; } af;
        const u16* p = &lw[(j * 160 + s * 32 + ln) * 68 + cc * 16 + hi * 8];
        af.d[0] = *(const u32x2*)p; af.d[1] = *(const u32x2*)(p + 4);
#pragma unroll
        for (int u = 0; u < 2; ++u)
          acc[s][u] = __builtin_amdgcn_mfma_f32_32x32x16_f16(af.v, bf[u].v, acc[s][u], 0, 0, 0);
      }
    }
    __syncthreads();
  }
  // epilogue 1: V rows (rt < 512) -> vtb[b][o][n] bf16
#pragma unroll
  for (int s = 0; s < 5; ++s) {
    int rt = j * 160 + s * 32;
    if (rt < 512) {
#pragma unroll
      for (int u = 0; u < 2; ++u) {
        int n = nb * 128 + i * 64 + u * 32 + ln;
#pragma unroll
        for (int r = 0; r < 16; ++r) {
          int o = rt + (r & 3) + 8 * (r >> 2) + 4 * hi;
          vtb[((size_t)(b * 512 + o)) * 4096 + n] = f2bf(acc[s][u][r]);
        }
      }
    }
  }
  // epilogue 2: QK rows (rt >= 512) -> qkl[n][m] f16 in LDS (over lw), then coalesced write
  u16* qkl = lw;
  if (j == 3) {
#pragma unroll
    for (int s = 1; s < 5; ++s) {
      int mbase = (s - 1) * 32;
#pragma unroll
      for (int u = 0; u < 2; ++u) {
        int nl = i * 64 + u * 32 + ln;
#pragma unroll
        for (int r = 0; r < 16; ++r) {
          int m = mbase + (r & 3) + 8 * (r >> 2) + 4 * hi;
          qkl[nl * 132 + m] = f2h(acc[s][u][r]);
        }
      }
    }
  }
  __syncthreads();
  {
    int n2 = t >> 2, ch = t & 3;
    u16* dst = qkb + (b4096 + nb * 128 + n2) * 128 + ch * 32;
#pragma unroll
    for (int g = 0; g < 4; ++g) {
      u32x2 d0 = *(const u32x2*)(&qkl[n2 * 132 + ch * 32 + g * 8]);
      u32x2 d1 = *(const u32x2*)(&qkl[n2 * 132 + ch * 32 + g * 8 + 4]);
      *(u32x4*)(dst + g * 8) = u32x4{d0[0], d0[1], d1[0], d1[1]};
    }
  }
}

// ------------- kernel 2: flash attention, o-chunk 256, 136B-stride LDS (R12/R15, 190.6 us) -------------
__global__ __launch_bounds__(512, 1) void k_attn2(const u16* __restrict__ qk, const u16* __restrict__ vt,
                                                  const float* __restrict__ x, const float* __restrict__ gamma,
                                                  float* __restrict__ out){
  __shared__ char smem[87040];   // buf[i] at i*43520: K 64x136 @+0 (8704B), V 256x136 @+8704
  int bx = blockIdx.x;
  int orig = (bx & 7) * 32 + (bx >> 3);
  int combo = orig >> 4, qt = orig & 15;
  int b = combo >> 1, oc2 = combo & 1;
  int obase = oc2 * 256;
  int t = threadIdx.x, w = t >> 6, l = t & 63, hi = l >> 5, ln = l & 31;
  int q = qt * 256 + w * 32 + ln;
  size_t b4096 = (size_t)b * 4096;
  f16x8 qf[4];
  {
    const u16* qrow = qk + (b4096 + q) * 128;
#pragma unroll
    for (int ch = 0; ch < 4; ++ch) qf[ch] = *(const f16x8*)(qrow + ch * 16 + hi * 8);
  }
  int rowS = t >> 3, chS = t & 7;
  unsigned w8 = (unsigned)(rowS * 17 + chS * 2);
  unsigned rb8[4];
#pragma unroll
  for (int cc = 0; cc < 4; ++cc)
    rb8[cc] = (unsigned)(ln * 17 + cc * 4 + hi * 2);
  const u16* gK = qk + (b4096 + rowS) * 128 + 64 + chS * 8;
  const u16* gV0 = vt + ((size_t)(b * 512 + obase + rowS)) * 4096 + chS * 8;
  const u16* gV1 = gV0 + (size_t)64 * 4096;
  const u16* gV2 = gV0 + (size_t)128 * 4096;
  const u16* gV3 = gV0 + (size_t)192 * 4096;
  u32x4 kreg = *(const u32x4*)gK;
  u32x4 vr0 = *(const u32x4*)gV0, vr1 = *(const u32x4*)gV1;
  u32x4 vr2 = *(const u32x4*)gV2, vr3 = *(const u32x4*)gV3;
  {
    char* bp = smem;
    *(u32x2*)(bp + w8 * 8)              = u32x2{kreg[0], kreg[1]};
    *(u32x2*)(bp + w8 * 8 + 8)          = u32x2{kreg[2], kreg[3]};
    *(u32x2*)(bp + 8704  + w8 * 8)      = u32x2{vr0[0], vr0[1]};
    *(u32x2*)(bp + 8704  + w8 * 8 + 8)  = u32x2{vr0[2], vr0[3]};
    *(u32x2*)(bp + 17408 + w8 * 8)      = u32x2{vr1[0], vr1[1]};
    *(u32x2*)(bp + 17408 + w8 * 8 + 8)  = u32x2{vr1[2], vr1[3]};
    *(u32x2*)(bp + 26112 + w8 * 8)      = u32x2{vr2[0], vr2[1]};
    *(u32x2*)(bp + 26112 + w8 * 8 + 8)  = u32x2{vr2[2], vr2[3]};
    *(u32x2*)(bp + 34816 + w8 * 8)      = u32x2{vr3[0], vr3[1]};
    *(u32x2*)(bp + 34816 + w8 * 8 + 8)  = u32x2{vr3[2], vr3[3]};
  }
  gK += 8192; gV0 += 64; gV1 += 64; gV2 += 64; gV3 += 64;
  f32x16 acc[8] = {};
  float lacc = 0.0f;
  for (int kt = 0; kt < 64; ++kt) {
    __syncthreads();
    char* bufp = smem + (kt & 1) * 43520;
    char* bufn = smem + ((kt + 1) & 1) * 43520;
    if (kt < 63) {
      kreg = *(const u32x4*)gK;
      vr0 = *(const u32x4*)gV0; vr1 = *(const u32x4*)gV1;
      vr2 = *(const u32x4*)gV2; vr3 = *(const u32x4*)gV3;
      gK += 8192; gV0 += 64; gV1 += 64; gV2 += 64; gV3 += 64;
    }
    f32x16 s0 = {}, s1 = {};
    __builtin_amdgcn_s_setprio(1);
#pragma unroll
    for (int cc = 0; cc < 4; ++cc) {
      union { u32x2 d[2]; f16x8 v; } k0, k1;
      const char* p0 = bufp + rb8[cc] * 8;
      const char* p1 = p0 + 4352;
      k0.d[0] = *(const u32x2*)p0;  k0.d[1] = *(const u32x2*)(p0 + 8);
      k1.d[0] = *(const u32x2*)p1;  k1.d[1] = *(const u32x2*)(p1 + 8);
      s0 = __builtin_amdgcn_mfma_f32_32x32x16_f16(k0.v, qf[cc], s0, 0, 0, 0);
      s1 = __builtin_amdgcn_mfma_f32_32x32x16_f16(k1.v, qf[cc], s1, 0, 0, 0);
    }
    __builtin_amdgcn_s_setprio(0);
#pragma unroll
    for (int r = 0; r < 16; ++r) s0[r] = ex2(s0[r]);
#pragma unroll
    for (int r = 0; r < 16; ++r) s1[r] = ex2(s1[r]);
    {
      float p[16];
#pragma unroll
      for (int r = 0; r < 16; ++r) p[r] = s0[r] + s1[r];
#pragma unroll
      for (int d = 8; d >= 1; d >>= 1)
#pragma unroll
        for (int r = 0; r < d; ++r) p[r] += p[r + d];
      lacc += p[0];
    }
    unsigned c0[8], c1[8];
#pragma unroll
    for (int ii = 0; ii < 8; ++ii) c0[ii] = pk2bf(s0[2 * ii], s0[2 * ii + 1]);
#pragma unroll
    for (int ii = 0; ii < 8; ++ii) c1[ii] = pk2bf(s1[2 * ii], s1[2 * ii + 1]);
    PSWAP(c0[0], c0[2]); PSWAP(c0[1], c0[3]); PSWAP(c0[4], c0[6]); PSWAP(c0[5], c0[7]);
    PSWAP(c1[0], c1[2]); PSWAP(c1[1], c1[3]); PSWAP(c1[4], c1[6]); PSWAP(c1[5], c1[7]);
    union U8 { unsigned u[4]; bf16x8 v; } pa[4];
#pragma unroll
    for (int jj = 0; jj < 4; ++jj) { pa[0].u[jj] = c0[jj]; pa[1].u[jj] = c0[4 + jj]; pa[2].u[jj] = c1[jj]; pa[3].u[jj] = c1[4 + jj]; }
    __builtin_amdgcn_s_setprio(1);
#pragma unroll
    for (int kc = 0; kc < 4; ++kc) {
      const char* pv = bufp + 8704 + rb8[kc] * 8;
#pragma unroll
      for (int ot = 0; ot < 8; ++ot) {
        union { u32x2 d[2]; bf16x8 v; } vb;
        const char* p = pv + ot * 4352;
        vb.d[0] = *(const u32x2*)p;  vb.d[1] = *(const u32x2*)(p + 8);
        acc[ot] = __builtin_amdgcn_mfma_f32_32x32x16_bf16(pa[kc].v, vb.v, acc[ot], 0, 0, 0);
      }
    }
    __builtin_amdgcn_s_setprio(0);
    if (kt < 63) {
      *(u32x2*)(bufn + w8 * 8)              = u32x2{kreg[0], kreg[1]};
      *(u32x2*)(bufn + w8 * 8 + 8)          = u32x2{kreg[2], kreg[3]};
      *(u32x2*)(bufn + 8704  + w8 * 8)      = u32x2{vr0[0], vr0[1]};
      *(u32x2*)(bufn + 8704  + w8 * 8 + 8)  = u32x2{vr0[2], vr0[3]};
      *(u32x2*)(bufn + 17408 + w8 * 8)      = u32x2{vr1[0], vr1[1]};
      *(u32x2*)(bufn + 17408 + w8 * 8 + 8)  = u32x2{vr1[2], vr1[3]};
      *(u32x2*)(bufn + 26112 + w8 * 8)      = u32x2{vr2[0], vr2[1]};
      *(u32x2*)(bufn + 26112 + w8 * 8 + 8)  = u32x2{vr2[2], vr2[3]};
      *(u32x2*)(bufn + 34816 + w8 * 8)      = u32x2{vr3[0], vr3[1]};
      *(u32x2*)(bufn + 34816 + w8 * 8 + 8)  = u32x2{vr3[2], vr3[3]};
    }
  }
  float l_tot = lacc + __shfl_xor(lacc, 32);
  float sinv = gamma[0] / l_tot;
  __syncthreads();
  float* tb = (float*)smem + w * 1056;
#pragma unroll
  for (int ot = 0; ot < 8; ++ot) {
#pragma unroll
    for (int r = 0; r < 16; ++r) {
      int qr = (r & 3) + 8 * (r >> 2) + 4 * hi;
      tb[ln * 33 + qr] = acc[ot][r];
    }
#pragma unroll
    for (int it = 0; it < 16; ++it) {
      int orow = it * 2 + hi;
      float v = tb[orow * 33 + ln];
      size_t gi = (((size_t)(b * 512 + obase + ot * 32 + orow)) << 12) + (size_t)(qt * 256 + w * 32 + ln);
      out[gi] = sinv * v + x[gi];
    }
    __syncthreads();
  }
}

extern "C" void kernel_launch(void* const* d_in, const int* in_sizes, int n_in,
                              void* d_out, int out_size, void* d_ws, size_t ws_size,
                              hipStream_t stream) {
  (void)in_sizes; (void)n_in; (void)out_size; (void)ws_size;
  const float* x     = (const float*)d_in[0];
  const float* wb    = (const float*)d_in[1];
  const float* wc    = (const float*)d_in[2];
  const float* wd    = (const float*)d_in[3];
  const float* gamma = (const float*)d_in[4];
  float* out = (float*)d_out;
  char* ws = (char*)d_ws;
  u16* w16 = (u16*)ws;                    // 640 KB: fused weights f16 [640][512]
  u16* qkb = (u16*)(ws + 1048576);        //   8 MB: [B][N][Q(64)|K(64)] f16
  u16* vtb = (u16*)(ws + 9437184);        //  32 MB: V^T bf16 [B][C][N]
  k_wcvt <<<dim3(640), dim3(256), 0, stream>>>(wb, wc, wd, w16);
  k_fused<<<dim3(256), dim3(512), 0, stream>>>(x, w16, qkb, vtb);
  k_attn2<<<dim3(256), dim3(512), 0, stream>>>(qkb, vtb, x, gamma, out);
}

// Round 17
// 218.080 us; speedup vs baseline: 1.2474x; 1.0254x over previous
//
#include <hip/hip_runtime.h>

typedef unsigned short u16;
typedef _Float16 f16x8 __attribute__((ext_vector_type(8)));
typedef short bf16x8 __attribute__((ext_vector_type(8)));
typedef float f32x16 __attribute__((ext_vector_type(16)));
typedef unsigned int u32x4 __attribute__((ext_vector_type(4)));
typedef unsigned int u32x2 __attribute__((ext_vector_type(2)));

#define LOG2E 1.44269504088896340736f

static __device__ __forceinline__ u16 f2h(float f){
  union { _Float16 h; u16 u; } v; v.h = (_Float16)f; return v.u;
}
static __device__ __forceinline__ u16 f2bf(float f){
  union { float f; unsigned u; } v; v.f = f;
  return (u16)((v.u + 0x7fffu + ((v.u >> 16) & 1u)) >> 16);
}
static __device__ __forceinline__ unsigned pk2bf(float lo, float hi){
  unsigned r; asm("v_cvt_pk_bf16_f32 %0, %1, %2" : "=v"(r) : "v"(lo), "v"(hi)); return r;
}
static __device__ __forceinline__ float ex2(float x){
#if __has_builtin(__builtin_amdgcn_exp2f)
  return __builtin_amdgcn_exp2f(x);
#else
  return exp2f(x);
#endif
}
#define PSWAP(a, b) asm("v_permlane32_swap_b32 %0, %1" : "+v"(a), "+v"(b))

typedef __attribute__((address_space(3))) unsigned int lds_u32;
typedef __attribute__((address_space(1))) const unsigned int glob_u32;
#define GLL(gp, lp) __builtin_amdgcn_global_load_lds((glob_u32*)(gp), (lds_u32*)(lp), 16, 0, 0)

// B=8, C=512, N=4096, MID=64
// ---- kernel 0: w16[640][512] f16 = [Wd(512) ; LOG2E*Wb(64) ; Wc(64)] ----
__global__ __launch_bounds__(256) void k_wcvt(const float* __restrict__ wb, const float* __restrict__ wc,
                                              const float* __restrict__ wd, u16* __restrict__ w16){
  int row = blockIdx.x, t = threadIdx.x;
  const float* src; float sc;
  if (row < 512)      { src = wd + (size_t)row * 512;        sc = 1.0f;  }
  else if (row < 576) { src = wb + (size_t)(row - 512) * 512; sc = LOG2E; }
  else                { src = wc + (size_t)(row - 576) * 512; sc = 1.0f;  }
  float2 v = *(const float2*)(src + t * 2);
  unsigned pk = (unsigned)f2h(v.x * sc) | ((unsigned)f2h(v.y * sc) << 16);
  *(unsigned*)(w16 + (size_t)row * 512 + t * 2) = pk;
}

// ---- kernel 1: fused projections (x-stage double-buffered through registers) ----
__global__ __launch_bounds__(512, 1) void k_fused(const float* __restrict__ x, const u16* __restrict__ w16,
                                                  u16* __restrict__ qkb, u16* __restrict__ vtb){
  __shared__ u16 ltmp[64 * 140];   // [c][n] f16, stride 140 u16
  __shared__ u16 lx[128 * 68];     // [n][c] f16, stride 68 u16
  __shared__ u16 lw[640 * 68];     // [row][c] f16, stride 68 u16; reused as qkl in epilogue
  int bx = blockIdx.x;
  int b = bx >> 5, nb = bx & 31;
  int t = threadIdx.x, w = t >> 6, l = t & 63, hi = l >> 5, ln = l & 31;
  int i = w & 1, j = w >> 1;
  size_t b4096 = (size_t)b * 4096;
  f32x16 acc[5][2] = {};
  int cS = t >> 3, ncS = t & 7;
  int nT = t & 127, q4 = t >> 7;
  const float* xbase = x + ((size_t)(b * 512 + cS)) * 4096 + nb * 128 + ncS * 16;
  float4 xpre[4];
#pragma unroll
  for (int g = 0; g < 4; ++g) xpre[g] = *(const float4*)(xbase + g * 4);
  for (int kt = 0; kt < 8; ++kt) {
    int c0 = kt * 64;
    {
      u16* d = &ltmp[cS * 140 + ncS * 16];
#pragma unroll
      for (int g = 0; g < 4; ++g) {
        float4 v = xpre[g];
        unsigned lo = (unsigned)f2h(v.x) | ((unsigned)f2h(v.y) << 16);
        unsigned h2 = (unsigned)f2h(v.z) | ((unsigned)f2h(v.w) << 16);
        *(u32x2*)(d + g * 4) = u32x2{lo, h2};
      }
    }
#pragma unroll
    for (int k10 = 0; k10 < 10; ++k10) {
      int slot = t + 512 * k10;
      int row = slot >> 3, ch8 = slot & 7;
      u32x4 wv = *(const u32x4*)(w16 + (size_t)row * 512 + c0 + ch8 * 8);
      u16* d = &lw[row * 68 + ch8 * 8];
      *(u32x2*)d       = u32x2{wv[0], wv[1]};
      *(u32x2*)(d + 4) = u32x2{wv[2], wv[3]};
    }
    __syncthreads();
    if (kt < 7) {
      const float* xp = xbase + (size_t)(kt + 1) * 64 * 4096;
#pragma unroll
      for (int g = 0; g < 4; ++g) xpre[g] = *(const float4*)(xp + g * 4);
    }
    {
      u16 tmp[16];
#pragma unroll
      for (int k = 0; k < 16; ++k) tmp[k] = ltmp[(q4 * 16 + k) * 140 + nT];
      u16* d = &lx[nT * 68 + q4 * 16];
#pragma unroll
      for (int g = 0; g < 4; ++g) {
        unsigned lo = (unsigned)tmp[g * 4]     | ((unsigned)tmp[g * 4 + 1] << 16);
        unsigned h2 = (unsigned)tmp[g * 4 + 2] | ((unsigned)tmp[g * 4 + 3] << 16);
        *(u32x2*)(d + g * 4) = u32x2{lo, h2};
      }
    }
    __syncthreads();
#pragma unroll
    for (int cc = 0; cc < 4; ++cc) {
      union { u32x2 d[2]; f16x8 v; } bf[2];
#pragma unroll
      for (int u = 0; u < 2; ++u) {
        const u16* p = &lx[(i * 64 + u * 32 + ln) * 68 + cc * 16 + hi * 8];
        bf[u].d[0] = *(const u32x2*)p; bf[u].d[1] = *(const u32x2*)(p + 4);
      }
#pragma unroll
      for (int s = 0; s < 5; ++s) {
        union { u32x2 d[2]; f16x8 v; } af;
        const u16* p = &lw[(j * 160 + s * 32 + ln) * 68 + cc * 16 + hi * 8];
        af.d[0] = *(const u32x2*)p; af.d[1] = *(const u32x2*)(p + 4);
#pragma unroll
        for (int u = 0; u < 2; ++u)
          acc[s][u] = __builtin_amdgcn_mfma_f32_32x32x16_f16(af.v, bf[u].v, acc[s][u], 0, 0, 0);
      }
    }
    __syncthreads();
  }
#pragma unroll
  for (int s = 0; s < 5; ++s) {
    int rt = j * 160 + s * 32;
    if (rt < 512) {
#pragma unroll
      for (int u = 0; u < 2; ++u) {
        int n = nb * 128 + i * 64 + u * 32 + ln;
#pragma unroll
        for (int r = 0; r < 16; ++r) {
          int o = rt + (r & 3) + 8 * (r >> 2) + 4 * hi;
          vtb[((size_t)(b * 512 + o)) * 4096 + n] = f2bf(acc[s][u][r]);
        }
      }
    }
  }
  u16* qkl = lw;
  if (j == 3) {
#pragma unroll
    for (int s = 1; s < 5; ++s) {
      int mbase = (s - 1) * 32;
#pragma unroll
      for (int u = 0; u < 2; ++u) {
        int nl = i * 64 + u * 32 + ln;
#pragma unroll
        for (int r = 0; r < 16; ++r) {
          int m = mbase + (r & 3) + 8 * (r >> 2) + 4 * hi;
          qkl[nl * 132 + m] = f2h(acc[s][u][r]);
        }
      }
    }
  }
  __syncthreads();
  {
    int n2 = t >> 2, ch = t & 3;
    u16* dst = qkb + (b4096 + nb * 128 + n2) * 128 + ch * 32;
#pragma unroll
    for (int g = 0; g < 4; ++g) {
      u32x2 d0 = *(const u32x2*)(&qkl[n2 * 132 + ch * 32 + g * 8]);
      u32x2 d1 = *(const u32x2*)(&qkl[n2 * 132 + ch * 32 + g * 8 + 4]);
      *(u32x4*)(dst + g * 8) = u32x4{d0[0], d0[1], d1[0], d1[1]};
    }
  }
}

// ------------- kernel 2: flash attention, o-chunk 256, GLL staging + XOR-swizzle reads -------------
// P = exp2(S), no max/stats. grid 256 XCD-chunked. 8 waves x 32 q; KV tile 64.
// global_load_lds direct staging (linear LDS rows [row][128B]; inverse-swizzled global SOURCE;
// XOR-swizzled b128 READS — pattern correctness-proven in R9). Double buffer, 1 barrier/iter.
__global__ __launch_bounds__(512, 1) void k_attn2(const u16* __restrict__ qk, const u16* __restrict__ vt,
                                                  const float* __restrict__ x, const float* __restrict__ gamma,
                                                  float* __restrict__ out){
  __shared__ char smem[81920];   // buf[i] at i*40960: K [64][128B] @+0, V [256][128B] @+8192
  int bx = blockIdx.x;
  int orig = (bx & 7) * 32 + (bx >> 3);
  int combo = orig >> 4, qt = orig & 15;
  int b = combo >> 1, oc2 = combo & 1;
  int obase = oc2 * 256;
  int t = threadIdx.x, w = t >> 6, l = t & 63, hi = l >> 5, ln = l & 31;
  int q = qt * 256 + w * 32 + ln;
  size_t b4096 = (size_t)b * 4096;
  // Q B-fragments (log2e folded in k_pqk-equivalent = k_fused)
  f16x8 qf[4];
  {
    const u16* qrow = qk + (b4096 + q) * 128;
#pragma unroll
    for (int ch = 0; ch < 4; ++ch) qf[ch] = *(const f16x8*)(qrow + ch * 16 + hi * 8);
  }
  // XOR-swizzled b128 read offsets (R8-proven)
  unsigned rb[4];
#pragma unroll
  for (int cc = 0; cc < 4; ++cc)
    rb[cc] = (unsigned)(ln * 128 + (((cc << 5) | (hi << 4)) ^ ((ln & 7) << 4)));
  // GLL source: thread t fills LDS slot (row=t>>3, chunk=t&7); global chunk = (t&7)^(row&7)
  int row = t >> 3;
  int ch2 = ((t & 7) ^ (row & 7)) * 8;
  const u16* gK = qk + (b4096 + row) * 128 + 64 + ch2;
  const u16* gV = vt + ((size_t)(b * 512 + obase + row)) * 4096 + ch2;
  unsigned ldsW = (unsigned)(w * 1024);   // per-wave dest base (lane x 16B implicit)
  // prologue: tile 0 -> buf0
  GLL(gK,            smem + ldsW);
  GLL(gV,            smem + 8192  + ldsW);
  GLL(gV + 262144,   smem + 16384 + ldsW);
  GLL(gV + 524288,   smem + 24576 + ldsW);
  GLL(gV + 786432,   smem + 32768 + ldsW);
  gK += 8192; gV += 64;
  f32x16 acc[8] = {};
  float lacc = 0.0f;
  for (int kt = 0; kt < 64; ++kt) {
    __syncthreads();   // drains GLL -> buf[kt&1] ready; prior reads of buf[(kt+1)&1] done
    char* bufp = smem + (kt & 1) * 40960;
    if (kt < 63) {     // issue next tile into other buffer; flies during this iter's compute
      char* bufn = smem + ((kt + 1) & 1) * 40960;
      GLL(gK,            bufn + ldsW);
      GLL(gV,            bufn + 8192  + ldsW);
      GLL(gV + 262144,   bufn + 16384 + ldsW);
      GLL(gV + 524288,   bufn + 24576 + ldsW);
      GLL(gV + 786432,   bufn + 32768 + ldsW);
      gK += 8192; gV += 64;
    }
    // S^T = K * Q^T : lane holds 32 scores for q=ln (hi splits k 0-31 / 32-63)
    f32x16 s0 = {}, s1 = {};
    __builtin_amdgcn_s_setprio(1);
#pragma unroll
    for (int cc = 0; cc < 4; ++cc) {
      f16x8 k0 = *(const f16x8*)(bufp + rb[cc]);
      f16x8 k1 = *(const f16x8*)(bufp + 4096 + rb[cc]);
      s0 = __builtin_amdgcn_mfma_f32_32x32x16_f16(k0, qf[cc], s0, 0, 0, 0);
      s1 = __builtin_amdgcn_mfma_f32_32x32x16_f16(k1, qf[cc], s1, 0, 0, 0);
    }
    __builtin_amdgcn_s_setprio(0);
    // P = exp2(S), tree row-sum
#pragma unroll
    for (int r = 0; r < 16; ++r) s0[r] = ex2(s0[r]);
#pragma unroll
    for (int r = 0; r < 16; ++r) s1[r] = ex2(s1[r]);
    {
      float p[16];
#pragma unroll
      for (int r = 0; r < 16; ++r) p[r] = s0[r] + s1[r];
#pragma unroll
      for (int d = 8; d >= 1; d >>= 1)
#pragma unroll
        for (int r = 0; r < d; ++r) p[r] += p[r + d];
      lacc += p[0];
    }
    // pack P -> bf16 A-fragments via cvt_pk + permlane32_swap
    unsigned c0[8], c1[8];
#pragma unroll
    for (int ii = 0; ii < 8; ++ii) c0[ii] = pk2bf(s0[2 * ii], s0[2 * ii + 1]);
#pragma unroll
    for (int ii = 0; ii < 8; ++ii) c1[ii] = pk2bf(s1[2 * ii], s1[2 * ii + 1]);
    PSWAP(c0[0], c0[2]); PSWAP(c0[1], c0[3]); PSWAP(c0[4], c0[6]); PSWAP(c0[5], c0[7]);
    PSWAP(c1[0], c1[2]); PSWAP(c1[1], c1[3]); PSWAP(c1[4], c1[6]); PSWAP(c1[5], c1[7]);
    union U8 { unsigned u[4]; bf16x8 v; } pa[4];
#pragma unroll
    for (int jj = 0; jj < 4; ++jj) { pa[0].u[jj] = c0[jj]; pa[1].u[jj] = c0[4 + jj]; pa[2].u[jj] = c1[jj]; pa[3].u[jj] = c1[4 + jj]; }
    // PV
    __builtin_amdgcn_s_setprio(1);
#pragma unroll
    for (int kc = 0; kc < 4; ++kc) {
      const char* pv = bufp + 8192 + rb[kc];
#pragma unroll
      for (int ot = 0; ot < 8; ++ot) {
        bf16x8 vb = *(const bf16x8*)(pv + ot * 4096);
        acc[ot] = __builtin_amdgcn_mfma_f32_32x32x16_bf16(pa[kc].v, vb, acc[ot], 0, 0, 0);
      }
    }
    __builtin_amdgcn_s_setprio(0);
  }
  // epilogue: l per q-row, scale = gamma/l; transpose 32x32 tiles via per-wave LDS; coalesced store
  float l_tot = lacc + __shfl_xor(lacc, 32);
  float sinv = gamma[0] / l_tot;
  __syncthreads();
  float* tb = (float*)smem + w * 1056;  // 8x4224B = 33792 <= buf0 (last tile was buf1)
#pragma unroll
  for (int ot = 0; ot < 8; ++ot) {
#pragma unroll
    for (int r = 0; r < 16; ++r) {
      int qr = (r & 3) + 8 * (r >> 2) + 4 * hi;
      tb[ln * 33 + qr] = acc[ot][r];
    }
#pragma unroll
    for (int it = 0; it < 16; ++it) {
      int orow = it * 2 + hi;
      float v = tb[orow * 33 + ln];
      size_t gi = (((size_t)(b * 512 + obase + ot * 32 + orow)) << 12) + (size_t)(qt * 256 + w * 32 + ln);
      out[gi] = sinv * v + x[gi];
    }
    __syncthreads();
  }
}

extern "C" void kernel_launch(void* const* d_in, const int* in_sizes, int n_in,
                              void* d_out, int out_size, void* d_ws, size_t ws_size,
                              hipStream_t stream) {
  (void)in_sizes; (void)n_in; (void)out_size; (void)ws_size;
  const float* x     = (const float*)d_in[0];
  const float* wb    = (const float*)d_in[1];
  const float* wc    = (const float*)d_in[2];
  const float* wd    = (const float*)d_in[3];
  const float* gamma = (const float*)d_in[4];
  float* out = (float*)d_out;
  char* ws = (char*)d_ws;
  u16* w16 = (u16*)ws;                    // 640 KB: fused weights f16 [640][512]
  u16* qkb = (u16*)(ws + 1048576);        //   8 MB: [B][N][Q(64)|K(64)] f16
  u16* vtb = (u16*)(ws + 9437184);        //  32 MB: V^T bf16 [B][C][N]
  k_wcvt <<<dim3(640), dim3(256), 0, stream>>>(wb, wc, wd, w16);
  k_fused<<<dim3(256), dim3(512), 0, stream>>>(x, w16, qkb, vtb);
  k_attn2<<<dim3(256), dim3(512), 0, stream>>>(qkb, vtb, x, gamma, out);
}